// Round 6
// baseline (106.024 us; speedup 1.0000x reference)
//
#include <hip/hip_runtime.h>
#include <math.h>
#include <float.h>
#include <limits.h>

#define CS   128            // points per chunk
#define CT   16             // chunks per K1 block
#define TILE_PTS (CT * CS)  // 2048 staged points per K1 block
#define CSP  129            // padded chunk stride in float4 (bank-balanced)
#define QB1  32             // queries per K1 block
#define QT   8              // queries per wave in K1
#define MARGIN 0.05f

// lexicographic (d, idx) sorted-3 insert (matches reference top_k tie-break)
__device__ __forceinline__ void ins3(float d, int ix,
    float& d0, float& d1, float& d2, int& i0, int& i1, int& i2)
{
    bool l2 = (d < d2) || (d == d2 && ix < i2);
    if (l2) {
        bool l1 = (d < d1) || (d == d1 && ix < i1);
        if (l1) {
            d2 = d1; i2 = i1;
            bool l0 = (d < d0) || (d == d0 && ix < i0);
            if (l0) { d1 = d0; i1 = i0; d0 = d; i0 = ix; }
            else    { d1 = d;  i1 = ix; }
        } else { d2 = d; i2 = ix; }
    }
}

// branchless sorted-3 insert, values only: min / med3 / med3
__device__ __forceinline__ void sins(float d, float& a0, float& a1, float& a2)
{
    float n1 = __builtin_amdgcn_fmed3f(a0, a1, d);
    float n2 = __builtin_amdgcn_fmed3f(a1, a2, d);
    a0 = fminf(a0, d);
    a1 = n1;
    a2 = n2;
}

// pose_0to1 = inv(pose1) @ pose0 (SE3 analytic)
__device__ __forceinline__ void pose_rel(const float* __restrict__ P0,
                                         const float* __restrict__ P1,
                                         float R[3][3], float tv[3])
{
    float dt0 = P0[3]  - P1[3];
    float dt1 = P0[7]  - P1[7];
    float dt2 = P0[11] - P1[11];
    #pragma unroll
    for (int i = 0; i < 3; ++i) {
        float a0 = P1[i], a1 = P1[4 + i], a2 = P1[8 + i];   // col i of R1
        #pragma unroll
        for (int j = 0; j < 3; ++j)
            R[i][j] = fmaf(a2, P0[8 + j], fmaf(a1, P0[4 + j], a0 * P0[j]));
        tv[i] = fmaf(a2, dt2, fmaf(a1, dt1, a0 * dt0));
    }
}

// ---------------- K1: per-(query, chunk) key-min table ----------------
// key(q,m) = r2 - 2*cross  (q2 dropped: constant per query, order-preserving)
__launch_bounds__(256, 4)
__global__ void knn_phaseA(const float* __restrict__ pc0,
                           const float* __restrict__ pc1,
                           const float* __restrict__ pose0,
                           const float* __restrict__ pose1,
                           float* __restrict__ cmin,
                           int B, int N, int M, int cstride)
{
    __shared__ float4 tile[CT * CSP];   // (-2x,-2y,-2z,r2), chunk-major padded
    __shared__ float4 qd[QB1];          // (qx,qy,qz,q2)

    const int tid = threadIdx.x;
    const int b   = blockIdx.z;
    const int ctb = blockIdx.y;               // chunk-tile index
    const int qb  = blockIdx.x * QB1;         // first query of block
    const int pbase = ctb * TILE_PTS;         // first staged point

    // ---- stage 32 queries (transform) into LDS ----
    if (tid < QB1) {
        float R[3][3], tv[3];
        pose_rel(pose0 + b * 16, pose1 + b * 16, R, tv);
        int qg0 = qb + tid;
        int qg  = (qg0 < N) ? qg0 : (N - 1);
        const float px = pc0[(size_t)(b * N + qg) * 3 + 0];
        const float py = pc0[(size_t)(b * N + qg) * 3 + 1];
        const float pz = pc0[(size_t)(b * N + qg) * 3 + 2];
        float qx = fmaf(R[0][2], pz, fmaf(R[0][1], py, R[0][0] * px)) + tv[0];
        float qy = fmaf(R[1][2], pz, fmaf(R[1][1], py, R[1][0] * px)) + tv[1];
        float qz = fmaf(R[2][2], pz, fmaf(R[2][1], py, R[2][0] * px)) + tv[2];
        qd[tid] = make_float4(qx, qy, qz,
                              (qx * qx + qy * qy) + qz * qz);
    }

    // ---- stage 2048 points: thread t loads points t+k*256 (coalesced) ----
    #pragma unroll
    for (int k = 0; k < TILE_PTS / 256; ++k) {
        const int pl = tid + k * 256;
        const int p  = pbase + pl;
        float4 v;
        if (p < M) {
            const float* pp = pc1 + (size_t)(b * M + p) * 3;
            float x = pp[0], y = pp[1], z = pp[2];
            v = make_float4(-2.0f * x, -2.0f * y, -2.0f * z,
                            (x * x + y * y) + z * z);
        } else {
            v = make_float4(0.f, 0.f, 0.f, FLT_MAX);
        }
        tile[(pl >> 7) * CSP + (pl & (CS - 1))] = v;
    }
    __syncthreads();

    // ---- scan: wave w handles queries w*8..w*8+7; lane = (part, chunk) ----
    const int w    = tid >> 6;
    const int lane = tid & 63;
    const int cl   = lane & 15;       // local chunk
    const int part = lane >> 4;       // quarter of the chunk (32 pts)

    float4 q0 = qd[w * QT + 0], q1 = qd[w * QT + 1];
    float4 q2 = qd[w * QT + 2], q3 = qd[w * QT + 3];
    float4 q4 = qd[w * QT + 4], q5 = qd[w * QT + 5];
    float4 q6 = qd[w * QT + 6], q7 = qd[w * QT + 7];

    float m0 = FLT_MAX, m1 = FLT_MAX, m2 = FLT_MAX, m3 = FLT_MAX;
    float m4 = FLT_MAX, m5 = FLT_MAX, m6 = FLT_MAX, m7 = FLT_MAX;

    const float4* tp = &tile[cl * CSP + part * 32];
    #pragma unroll 8
    for (int i = 0; i < 32; ++i) {
        const float4 v = tp[i];
        m0 = fminf(m0, fmaf(q0.x, v.x, fmaf(q0.y, v.y, fmaf(q0.z, v.z, v.w))));
        m1 = fminf(m1, fmaf(q1.x, v.x, fmaf(q1.y, v.y, fmaf(q1.z, v.z, v.w))));
        m2 = fminf(m2, fmaf(q2.x, v.x, fmaf(q2.y, v.y, fmaf(q2.z, v.z, v.w))));
        m3 = fminf(m3, fmaf(q3.x, v.x, fmaf(q3.y, v.y, fmaf(q3.z, v.z, v.w))));
        m4 = fminf(m4, fmaf(q4.x, v.x, fmaf(q4.y, v.y, fmaf(q4.z, v.z, v.w))));
        m5 = fminf(m5, fmaf(q5.x, v.x, fmaf(q5.y, v.y, fmaf(q5.z, v.z, v.w))));
        m6 = fminf(m6, fmaf(q6.x, v.x, fmaf(q6.y, v.y, fmaf(q6.z, v.z, v.w))));
        m7 = fminf(m7, fmaf(q7.x, v.x, fmaf(q7.y, v.y, fmaf(q7.z, v.z, v.w))));
    }

    // merge the 4 parts of each chunk (lane bits 4..5)
    #pragma unroll
    for (int msk = 16; msk <= 32; msk <<= 1) {
        m0 = fminf(m0, __shfl_xor(m0, msk));
        m1 = fminf(m1, __shfl_xor(m1, msk));
        m2 = fminf(m2, __shfl_xor(m2, msk));
        m3 = fminf(m3, __shfl_xor(m3, msk));
        m4 = fminf(m4, __shfl_xor(m4, msk));
        m5 = fminf(m5, __shfl_xor(m5, msk));
        m6 = fminf(m6, __shfl_xor(m6, msk));
        m7 = fminf(m7, __shfl_xor(m7, msk));
    }

    if (part == 0) {
        const int cg = ctb * CT + cl;         // global chunk id
        float mv[QT] = {m0, m1, m2, m3, m4, m5, m6, m7};
        #pragma unroll
        for (int t = 0; t < QT; ++t) {
            int qg0 = qb + w * QT + t;
            int qg  = (qg0 < N) ? qg0 : (N - 1);
            cmin[((size_t)b * N + qg) * cstride + cg] = mv[t];
        }
    }
}

// ---------------- K2: threshold + exact rescan + outputs ----------------
__launch_bounds__(256, 4)
__global__ void knn_select(const float* __restrict__ pc0,
                           const float* __restrict__ pc1,
                           const float* __restrict__ flow1,
                           const float* __restrict__ pose0,
                           const float* __restrict__ pose1,
                           const float* __restrict__ cmin,
                           float* __restrict__ out,
                           int B, int N, int M, int cstride)
{
    const int tid  = threadIdx.x;
    const int w    = tid >> 6;
    const int lane = tid & 63;
    const int b    = blockIdx.y;
    const int q    = blockIdx.x * 4 + w;
    if (q >= N) return;

    // ---- query transform (redundant per lane) + pose_flow ----
    float R[3][3], tv[3];
    pose_rel(pose0 + b * 16, pose1 + b * 16, R, tv);
    const float px = pc0[(size_t)(b * N + q) * 3 + 0];
    const float py = pc0[(size_t)(b * N + q) * 3 + 1];
    const float pz = pc0[(size_t)(b * N + q) * 3 + 2];
    const float qx = fmaf(R[0][2], pz, fmaf(R[0][1], py, R[0][0] * px)) + tv[0];
    const float qy = fmaf(R[1][2], pz, fmaf(R[1][1], py, R[1][0] * px)) + tv[1];
    const float qz = fmaf(R[2][2], pz, fmaf(R[2][1], py, R[2][0] * px)) + tv[2];
    const float q2 = (qx * qx + qy * qy) + qz * qz;

    if (lane == 0) {
        size_t pf = (size_t)B * N * 3 + (size_t)(b * N + q) * 3;
        out[pf + 0] = qx - px;
        out[pf + 1] = qy - py;
        out[pf + 2] = qz - pz;
    }

    // ---- per-lane chunk-min, 3rd-smallest via butterfly ----
    const int ncc = (M + CS - 1) / CS;          // valid chunks (64 here)
    float key = (lane < ncc) ? cmin[((size_t)b * N + q) * cstride + lane]
                             : FLT_MAX;
    float a0 = key, a1 = FLT_MAX, a2 = FLT_MAX;
    #pragma unroll
    for (int msk = 1; msk <= 32; msk <<= 1) {
        float o0 = __shfl_xor(a0, msk);
        float o1 = __shfl_xor(a1, msk);
        float o2 = __shfl_xor(a2, msk);
        sins(o0, a0, a1, a2);
        sins(o1, a0, a1, a2);
        sins(o2, a0, a1, a2);
    }
    const float thr = a2 + MARGIN;
    unsigned long long mask = __ballot(key <= thr);   // uniform

    // ---- dense rescan of selected chunks (64 lanes, 2 rounds/chunk) ----
    float d0 = FLT_MAX, d1 = FLT_MAX, d2v = FLT_MAX;
    int   i0 = INT_MAX, i1 = INT_MAX, i2v = INT_MAX;
    while (mask) {
        const int ck = (int)__builtin_ctzll(mask);
        mask &= mask - 1;
        #pragma unroll
        for (int r = 0; r < CS / 64; ++r) {
            const int m = ck * CS + r * 64 + lane;
            if (m < M) {
                const float* pp = pc1 + (size_t)(b * M + m) * 3;
                float x = pp[0], y = pp[1], z = pp[2];
                float r2 = (x * x + y * y) + z * z;
                float cr = fmaf(qz, z, fmaf(qy, y, qx * x));
                float dd = fmaf(-2.0f, cr, q2 + r2);     // exact ref rounding
                ins3(dd, m, d0, d1, d2v, i0, i1, i2v);
            }
        }
    }

    // ---- merge 64 lanes ----
    #pragma unroll
    for (int msk = 1; msk <= 32; msk <<= 1) {
        float o0 = __shfl_xor(d0, msk), o1 = __shfl_xor(d1, msk), o2 = __shfl_xor(d2v, msk);
        int   p0 = __shfl_xor(i0, msk), p1 = __shfl_xor(i1, msk), p2 = __shfl_xor(i2v, msk);
        ins3(o0, p0, d0, d1, d2v, i0, i1, i2v);
        ins3(o1, p1, d0, d1, d2v, i0, i1, i2v);
        ins3(o2, p2, d0, d1, d2v, i0, i1, i2v);
    }

    if (lane == 0) {
        float dd0 = sqrtf(fmaxf(d0, 0.f));
        float dd1 = sqrtf(fmaxf(d1, 0.f));
        float dd2 = sqrtf(fmaxf(d2v, 0.f));
        float w0 = 1.0f / (dd0 + 1e-8f);
        float w1 = 1.0f / (dd1 + 1e-8f);
        float w2 = 1.0f / (dd2 + 1e-8f);
        float wsum = (w0 + w1) + w2;
        w0 /= wsum; w1 /= wsum; w2 /= wsum;

        const float* f0 = flow1 + (size_t)(b * M + i0) * 3;
        const float* f1 = flow1 + (size_t)(b * M + i1) * 3;
        const float* f2 = flow1 + (size_t)(b * M + i2v) * 3;

        const size_t ob = (size_t)(b * N + q) * 3;
        #pragma unroll
        for (int c = 0; c < 3; ++c) {
            float p0 = w0 * f0[c];
            float p1 = w1 * f1[c];
            float p2 = w2 * f2[c];
            out[ob + c] = (p0 + p1) + p2;
        }
    }
}

extern "C" void kernel_launch(void* const* d_in, const int* in_sizes, int n_in,
                              void* d_out, int out_size, void* d_ws, size_t ws_size,
                              hipStream_t stream) {
    const float* pc0   = (const float*)d_in[0];
    const float* pc1   = (const float*)d_in[1];
    const float* flow1 = (const float*)d_in[2];
    const float* pose0 = (const float*)d_in[3];
    const float* pose1 = (const float*)d_in[4];
    float* out = (float*)d_out;

    const int B = in_sizes[3] / 16;
    const int N = in_sizes[0] / (3 * B);
    const int M = in_sizes[1] / (3 * B);

    const int nct     = (M + TILE_PTS - 1) / TILE_PTS;   // chunk-tiles
    const int cstride = nct * CT;                        // chunk-min row stride

    float* cmin = (float*)d_ws;   // B*N*cstride floats (4 MB at 2x8192x64)

    dim3 g1((N + QB1 - 1) / QB1, nct, B);
    knn_phaseA<<<g1, dim3(256), 0, stream>>>(pc0, pc1, pose0, pose1,
                                             cmin, B, N, M, cstride);

    dim3 g2((N + 3) / 4, B);
    knn_select<<<g2, dim3(256), 0, stream>>>(pc0, pc1, flow1, pose0, pose1,
                                             cmin, out, B, N, M, cstride);
}

// Round 7
// 39.715 us; speedup vs baseline: 2.6696x; 2.6696x over previous
//
#include <hip/hip_runtime.h>
#include <math.h>
#include <float.h>
#include <limits.h>

#define CS   128            // points per chunk
#define CT   16             // chunks per K1 block
#define TILE_PTS (CT * CS)  // 2048 staged points per K1 block
#define CSP  129            // padded chunk stride in float4 (bank-balanced)
#define QB1  32             // queries per K1 block
#define QT   8              // queries per wave in K1
#define MARGIN 0.05f
typedef unsigned long long ull;
#define KMAX 0xFFFFFFFFFFFFFFFFull

// monotone float -> ordered u32 (handles negatives)
__device__ __forceinline__ unsigned int ford(float f) {
    unsigned int b = __float_as_uint(f);
    return b ^ (((unsigned int)((int)b >> 31)) | 0x80000000u);
}
// inverse
__device__ __forceinline__ float funord(unsigned int u) {
    unsigned int m = ((u >> 31) - 1u) | 0x80000000u;
    return __uint_as_float(u ^ m);
}

__device__ __forceinline__ ull umin64(ull a, ull b) { return a < b ? a : b; }
__device__ __forceinline__ ull umax64(ull a, ull b) { return a > b ? a : b; }

// branchless sorted-3 insert on u64 keys (k0<=k1<=k2)
__device__ __forceinline__ void ins3k(ull k, ull& k0, ull& k1, ull& k2) {
    ull n2 = umax64(k1, umin64(k2, k));   // med3(k1,k2,k)
    ull n1 = umax64(k0, umin64(k1, k));   // med3(k0,k1,k)
    k0 = umin64(k0, k);
    k1 = n1;
    k2 = n2;
}

__device__ __forceinline__ ull wmin64(ull k) {
    #pragma unroll
    for (int m = 1; m <= 32; m <<= 1) {
        ull o = __shfl_xor(k, m);
        k = o < k ? o : k;
    }
    return k;
}
__device__ __forceinline__ float wminf(float v) {
    #pragma unroll
    for (int m = 1; m <= 32; m <<= 1)
        v = fminf(v, __shfl_xor(v, m));
    return v;
}

// pose_0to1 = inv(pose1) @ pose0 (SE3 analytic)
__device__ __forceinline__ void pose_rel(const float* __restrict__ P0,
                                         const float* __restrict__ P1,
                                         float R[3][3], float tv[3])
{
    float dt0 = P0[3]  - P1[3];
    float dt1 = P0[7]  - P1[7];
    float dt2 = P0[11] - P1[11];
    #pragma unroll
    for (int i = 0; i < 3; ++i) {
        float a0 = P1[i], a1 = P1[4 + i], a2 = P1[8 + i];   // col i of R1
        #pragma unroll
        for (int j = 0; j < 3; ++j)
            R[i][j] = fmaf(a2, P0[8 + j], fmaf(a1, P0[4 + j], a0 * P0[j]));
        tv[i] = fmaf(a2, dt2, fmaf(a1, dt1, a0 * dt0));
    }
}

// ---------------- K1: per-(query, chunk) key-min table ----------------
// key(q,m) = r2 - 2*cross  (q2 dropped: constant per query, order-preserving)
__launch_bounds__(256, 4)
__global__ void knn_phaseA(const float* __restrict__ pc0,
                           const float* __restrict__ pc1,
                           const float* __restrict__ pose0,
                           const float* __restrict__ pose1,
                           float* __restrict__ cmin,
                           int B, int N, int M, int cstride)
{
    __shared__ float4 tile[CT * CSP];   // (-2x,-2y,-2z,r2), chunk-major padded
    __shared__ float4 qd[QB1];          // (qx,qy,qz,q2)

    const int tid = threadIdx.x;
    const int b   = blockIdx.z;
    const int ctb = blockIdx.y;               // chunk-tile index
    const int qb  = blockIdx.x * QB1;         // first query of block
    const int pbase = ctb * TILE_PTS;         // first staged point

    // ---- stage 32 queries (transform) into LDS ----
    if (tid < QB1) {
        float R[3][3], tv[3];
        pose_rel(pose0 + b * 16, pose1 + b * 16, R, tv);
        int qg0 = qb + tid;
        int qg  = (qg0 < N) ? qg0 : (N - 1);
        const float px = pc0[(size_t)(b * N + qg) * 3 + 0];
        const float py = pc0[(size_t)(b * N + qg) * 3 + 1];
        const float pz = pc0[(size_t)(b * N + qg) * 3 + 2];
        float qx = fmaf(R[0][2], pz, fmaf(R[0][1], py, R[0][0] * px)) + tv[0];
        float qy = fmaf(R[1][2], pz, fmaf(R[1][1], py, R[1][0] * px)) + tv[1];
        float qz = fmaf(R[2][2], pz, fmaf(R[2][1], py, R[2][0] * px)) + tv[2];
        qd[tid] = make_float4(qx, qy, qz,
                              (qx * qx + qy * qy) + qz * qz);
    }

    // ---- stage 2048 points, 4 pts (3x dwordx4) per thread per round ----
    #pragma unroll
    for (int k = 0; k < TILE_PTS / (256 * 4); ++k) {
        const int pl = (tid + k * 256) * 4;
        const int p  = pbase + pl;
        float4* dst = &tile[(pl >> 7) * CSP + (pl & (CS - 1))];
        if (p + 3 < M) {
            const float4* pf = (const float4*)(pc1 + (size_t)(b * M + p) * 3);
            float4 A = pf[0], Bv = pf[1], C = pf[2];
            dst[0] = make_float4(-2.f * A.x, -2.f * A.y, -2.f * A.z,
                                 (A.x * A.x + A.y * A.y) + A.z * A.z);
            dst[1] = make_float4(-2.f * A.w, -2.f * Bv.x, -2.f * Bv.y,
                                 (A.w * A.w + Bv.x * Bv.x) + Bv.y * Bv.y);
            dst[2] = make_float4(-2.f * Bv.z, -2.f * Bv.w, -2.f * C.x,
                                 (Bv.z * Bv.z + Bv.w * Bv.w) + C.x * C.x);
            dst[3] = make_float4(-2.f * C.y, -2.f * C.z, -2.f * C.w,
                                 (C.y * C.y + C.z * C.z) + C.w * C.w);
        } else {
            #pragma unroll
            for (int u = 0; u < 4; ++u) {
                int pp = p + u;
                float4 v;
                if (pp < M) {
                    const float* s = pc1 + (size_t)(b * M + pp) * 3;
                    float x = s[0], y = s[1], z = s[2];
                    v = make_float4(-2.f * x, -2.f * y, -2.f * z,
                                    (x * x + y * y) + z * z);
                } else {
                    v = make_float4(0.f, 0.f, 0.f, FLT_MAX);
                }
                dst[u] = v;
            }
        }
    }
    __syncthreads();

    // ---- scan: wave w handles queries w*8..w*8+7; lane = (part, chunk) ----
    const int w    = tid >> 6;
    const int lane = tid & 63;
    const int cl   = lane & 15;       // local chunk
    const int part = lane >> 4;       // quarter of the chunk (32 pts)

    float4 q0 = qd[w * QT + 0], q1 = qd[w * QT + 1];
    float4 q2 = qd[w * QT + 2], q3 = qd[w * QT + 3];
    float4 q4 = qd[w * QT + 4], q5 = qd[w * QT + 5];
    float4 q6 = qd[w * QT + 6], q7 = qd[w * QT + 7];

    float m0 = FLT_MAX, m1 = FLT_MAX, m2 = FLT_MAX, m3 = FLT_MAX;
    float m4 = FLT_MAX, m5 = FLT_MAX, m6 = FLT_MAX, m7 = FLT_MAX;

    const float4* tp = &tile[cl * CSP + part * 32];
    #pragma unroll 8
    for (int i = 0; i < 32; ++i) {
        const float4 v = tp[i];
        m0 = fminf(m0, fmaf(q0.x, v.x, fmaf(q0.y, v.y, fmaf(q0.z, v.z, v.w))));
        m1 = fminf(m1, fmaf(q1.x, v.x, fmaf(q1.y, v.y, fmaf(q1.z, v.z, v.w))));
        m2 = fminf(m2, fmaf(q2.x, v.x, fmaf(q2.y, v.y, fmaf(q2.z, v.z, v.w))));
        m3 = fminf(m3, fmaf(q3.x, v.x, fmaf(q3.y, v.y, fmaf(q3.z, v.z, v.w))));
        m4 = fminf(m4, fmaf(q4.x, v.x, fmaf(q4.y, v.y, fmaf(q4.z, v.z, v.w))));
        m5 = fminf(m5, fmaf(q5.x, v.x, fmaf(q5.y, v.y, fmaf(q5.z, v.z, v.w))));
        m6 = fminf(m6, fmaf(q6.x, v.x, fmaf(q6.y, v.y, fmaf(q6.z, v.z, v.w))));
        m7 = fminf(m7, fmaf(q7.x, v.x, fmaf(q7.y, v.y, fmaf(q7.z, v.z, v.w))));
    }

    // merge the 4 parts of each chunk (lane bits 4..5)
    #pragma unroll
    for (int msk = 16; msk <= 32; msk <<= 1) {
        m0 = fminf(m0, __shfl_xor(m0, msk));
        m1 = fminf(m1, __shfl_xor(m1, msk));
        m2 = fminf(m2, __shfl_xor(m2, msk));
        m3 = fminf(m3, __shfl_xor(m3, msk));
        m4 = fminf(m4, __shfl_xor(m4, msk));
        m5 = fminf(m5, __shfl_xor(m5, msk));
        m6 = fminf(m6, __shfl_xor(m6, msk));
        m7 = fminf(m7, __shfl_xor(m7, msk));
    }

    if (part == 0) {
        const int cg = ctb * CT + cl;         // global chunk id
        float mv[QT] = {m0, m1, m2, m3, m4, m5, m6, m7};
        #pragma unroll
        for (int t = 0; t < QT; ++t) {
            int qg0 = qb + w * QT + t;
            int qg  = (qg0 < N) ? qg0 : (N - 1);
            cmin[((size_t)b * N + qg) * cstride + cg] = mv[t];
        }
    }
}

// ---------------- K2: threshold + exact rescan + outputs ----------------
__launch_bounds__(256, 8)
__global__ void knn_select(const float* __restrict__ pc0,
                           const float* __restrict__ pc1,
                           const float* __restrict__ flow1,
                           const float* __restrict__ pose0,
                           const float* __restrict__ pose1,
                           const float* __restrict__ cmin,
                           float* __restrict__ out,
                           int B, int N, int M, int cstride)
{
    const int tid  = threadIdx.x;
    const int w    = tid >> 6;
    const int lane = tid & 63;
    const int b    = blockIdx.y;
    const int q    = blockIdx.x * 4 + w;
    if (q >= N) return;

    // issue chunk-min load early (latency overlaps pose math)
    const int ncc = (M + CS - 1) / CS;
    float key = (lane < ncc) ? cmin[((size_t)b * N + q) * cstride + lane]
                             : FLT_MAX;

    // ---- query transform (redundant per lane) + pose_flow ----
    float R[3][3], tv[3];
    pose_rel(pose0 + b * 16, pose1 + b * 16, R, tv);
    const float px = pc0[(size_t)(b * N + q) * 3 + 0];
    const float py = pc0[(size_t)(b * N + q) * 3 + 1];
    const float pz = pc0[(size_t)(b * N + q) * 3 + 2];
    const float qx = fmaf(R[0][2], pz, fmaf(R[0][1], py, R[0][0] * px)) + tv[0];
    const float qy = fmaf(R[1][2], pz, fmaf(R[1][1], py, R[1][0] * px)) + tv[1];
    const float qz = fmaf(R[2][2], pz, fmaf(R[2][1], py, R[2][0] * px)) + tv[2];
    const float q2 = (qx * qx + qy * qy) + qz * qz;

    if (lane == 0) {
        size_t pf = (size_t)B * N * 3 + (size_t)(b * N + q) * 3;
        out[pf + 0] = qx - px;
        out[pf + 1] = qy - py;
        out[pf + 2] = qz - pz;
    }

    // ---- threshold: 3 masked min passes (dup-masking only enlarges superset)
    float v = key;
    float t0 = wminf(v); v = (v == t0) ? FLT_MAX : v;
    float t1 = wminf(v); v = (v == t1) ? FLT_MAX : v;
    float t2 = wminf(v);
    const float thr = t2 + MARGIN;
    ull mask = __ballot(key <= thr);   // wave-uniform

    // ---- dense rescan of selected chunks; (d2,idx) packed in u64 keys ----
    ull k0 = KMAX, k1 = KMAX, k2 = KMAX;
    while (mask) {
        const int ck = (int)__builtin_ctzll(mask);
        mask &= mask - 1;
        #pragma unroll
        for (int r = 0; r < CS / 64; ++r) {
            const int m = ck * CS + r * 64 + lane;
            if (m < M) {
                const float* pp = pc1 + (size_t)(b * M + m) * 3;
                float x = pp[0], y = pp[1], z = pp[2];
                float r2 = (x * x + y * y) + z * z;
                float cr = fmaf(qz, z, fmaf(qy, y, qx * x));
                float dd = fmaf(-2.0f, cr, q2 + r2);     // exact ref rounding
                ull kk = ((ull)ford(dd) << 32) | (unsigned int)m;
                ins3k(kk, k0, k1, k2);
            }
        }
    }

    // ---- global top-3: three masked min passes over k0 ----
    ull g0 = wmin64(k0);
    { bool e = (k0 == g0); k0 = e ? k1 : k0; k1 = e ? k2 : k1; }
    ull g1 = wmin64(k0);
    { bool e = (k0 == g1); k0 = e ? k1 : k0; }
    ull g2 = wmin64(k0);

    if (lane == 0) {
        float D0 = funord((unsigned int)(g0 >> 32));
        float D1 = funord((unsigned int)(g1 >> 32));
        float D2 = funord((unsigned int)(g2 >> 32));
        int   i0 = (int)(unsigned int)g0;
        int   i1 = (int)(unsigned int)g1;
        int   i2 = (int)(unsigned int)g2;

        float dd0 = sqrtf(fmaxf(D0, 0.f));
        float dd1 = sqrtf(fmaxf(D1, 0.f));
        float dd2 = sqrtf(fmaxf(D2, 0.f));
        float w0 = 1.0f / (dd0 + 1e-8f);
        float w1 = 1.0f / (dd1 + 1e-8f);
        float w2 = 1.0f / (dd2 + 1e-8f);
        float wsum = (w0 + w1) + w2;
        w0 /= wsum; w1 /= wsum; w2 /= wsum;

        const float* f0 = flow1 + (size_t)(b * M + i0) * 3;
        const float* f1 = flow1 + (size_t)(b * M + i1) * 3;
        const float* f2 = flow1 + (size_t)(b * M + i2) * 3;

        const size_t ob = (size_t)(b * N + q) * 3;
        #pragma unroll
        for (int c = 0; c < 3; ++c) {
            float p0 = w0 * f0[c];
            float p1 = w1 * f1[c];
            float p2 = w2 * f2[c];
            out[ob + c] = (p0 + p1) + p2;
        }
    }
}

extern "C" void kernel_launch(void* const* d_in, const int* in_sizes, int n_in,
                              void* d_out, int out_size, void* d_ws, size_t ws_size,
                              hipStream_t stream) {
    const float* pc0   = (const float*)d_in[0];
    const float* pc1   = (const float*)d_in[1];
    const float* flow1 = (const float*)d_in[2];
    const float* pose0 = (const float*)d_in[3];
    const float* pose1 = (const float*)d_in[4];
    float* out = (float*)d_out;

    const int B = in_sizes[3] / 16;
    const int N = in_sizes[0] / (3 * B);
    const int M = in_sizes[1] / (3 * B);

    const int nct     = (M + TILE_PTS - 1) / TILE_PTS;   // chunk-tiles
    const int cstride = nct * CT;                        // chunk-min row stride

    float* cmin = (float*)d_ws;   // B*N*cstride floats (4 MB at 2x8192x64)

    dim3 g1((N + QB1 - 1) / QB1, nct, B);
    knn_phaseA<<<g1, dim3(256), 0, stream>>>(pc0, pc1, pose0, pose1,
                                             cmin, B, N, M, cstride);

    dim3 g2((N + 3) / 4, B);
    knn_select<<<g2, dim3(256), 0, stream>>>(pc0, pc1, flow1, pose0, pose1,
                                             cmin, out, B, N, M, cstride);
}

// Round 8
// 34.070 us; speedup vs baseline: 3.1120x; 1.1657x over previous
//
#include <hip/hip_runtime.h>
#include <math.h>
#include <float.h>
#include <limits.h>

#define CS   128            // points per chunk
#define CT   16             // chunks per K1 block
#define TILE_PTS (CT * CS)  // 2048 staged points per K1 block
#define CSP  129            // padded chunk stride in float4 (bank-balanced)
#define QB1  64             // queries per K1 block
#define QT   16             // queries per wave in K1
#define MARGIN 0.05f
typedef unsigned long long ull;
#define KMAX 0xFFFFFFFFFFFFFFFFull

// monotone float -> ordered u32 (handles negatives)
__device__ __forceinline__ unsigned int ford(float f) {
    unsigned int b = __float_as_uint(f);
    return b ^ (((unsigned int)((int)b >> 31)) | 0x80000000u);
}
__device__ __forceinline__ float funord(unsigned int u) {
    unsigned int m = ((u >> 31) - 1u) | 0x80000000u;
    return __uint_as_float(u ^ m);
}

__device__ __forceinline__ ull umin64(ull a, ull b) { return a < b ? a : b; }
__device__ __forceinline__ ull umax64(ull a, ull b) { return a > b ? a : b; }

// branchless sorted-3 insert on u64 keys (k0<=k1<=k2)
__device__ __forceinline__ void ins3k(ull k, ull& k0, ull& k1, ull& k2) {
    ull n2 = umax64(k1, umin64(k2, k));   // med3(k1,k2,k)
    ull n1 = umax64(k0, umin64(k1, k));   // med3(k0,k1,k)
    k0 = umin64(k0, k);
    k1 = n1;
    k2 = n2;
}

// branchless sorted-3 insert, f32 values only
__device__ __forceinline__ void sins(float d, float& a0, float& a1, float& a2)
{
    float n1 = __builtin_amdgcn_fmed3f(a0, a1, d);
    float n2 = __builtin_amdgcn_fmed3f(a1, a2, d);
    a0 = fminf(a0, d);
    a1 = n1;
    a2 = n2;
}

// pose_0to1 = inv(pose1) @ pose0 (SE3 analytic)
__device__ __forceinline__ void pose_rel(const float* __restrict__ P0,
                                         const float* __restrict__ P1,
                                         float R[3][3], float tv[3])
{
    float dt0 = P0[3]  - P1[3];
    float dt1 = P0[7]  - P1[7];
    float dt2 = P0[11] - P1[11];
    #pragma unroll
    for (int i = 0; i < 3; ++i) {
        float a0 = P1[i], a1 = P1[4 + i], a2 = P1[8 + i];   // col i of R1
        #pragma unroll
        for (int j = 0; j < 3; ++j)
            R[i][j] = fmaf(a2, P0[8 + j], fmaf(a1, P0[4 + j], a0 * P0[j]));
        tv[i] = fmaf(a2, dt2, fmaf(a1, dt1, a0 * dt0));
    }
}

// ---------------- K1: per-(query, chunk) key-min table ----------------
// key(q,m) = r2 - 2*cross  (q2 dropped: constant per query, order-preserving)
__launch_bounds__(256, 4)
__global__ void knn_phaseA(const float* __restrict__ pc0,
                           const float* __restrict__ pc1,
                           const float* __restrict__ pose0,
                           const float* __restrict__ pose1,
                           float* __restrict__ cmin,
                           int B, int N, int M, int cstride)
{
    __shared__ float4 tile[CT * CSP];   // (-2x,-2y,-2z,r2), chunk-major padded
    __shared__ float4 qd[QB1];          // (qx,qy,qz,q2)

    const int tid = threadIdx.x;
    const int b   = blockIdx.z;
    const int ctb = blockIdx.y;               // chunk-tile index
    const int qb  = blockIdx.x * QB1;         // first query of block
    const int pbase = ctb * TILE_PTS;         // first staged point

    // ---- stage 64 transformed queries into LDS ----
    if (tid < QB1) {
        float R[3][3], tv[3];
        pose_rel(pose0 + b * 16, pose1 + b * 16, R, tv);
        int qg0 = qb + tid;
        int qg  = (qg0 < N) ? qg0 : (N - 1);
        const float px = pc0[(size_t)(b * N + qg) * 3 + 0];
        const float py = pc0[(size_t)(b * N + qg) * 3 + 1];
        const float pz = pc0[(size_t)(b * N + qg) * 3 + 2];
        float qx = fmaf(R[0][2], pz, fmaf(R[0][1], py, R[0][0] * px)) + tv[0];
        float qy = fmaf(R[1][2], pz, fmaf(R[1][1], py, R[1][0] * px)) + tv[1];
        float qz = fmaf(R[2][2], pz, fmaf(R[2][1], py, R[2][0] * px)) + tv[2];
        qd[tid] = make_float4(qx, qy, qz,
                              (qx * qx + qy * qy) + qz * qz);
    }

    // ---- stage 2048 points, 4 pts (3x dwordx4) per thread per round ----
    #pragma unroll
    for (int k = 0; k < TILE_PTS / (256 * 4); ++k) {
        const int pl = (tid + k * 256) * 4;
        const int p  = pbase + pl;
        float4* dst = &tile[(pl >> 7) * CSP + (pl & (CS - 1))];
        if (p + 3 < M) {
            const float4* pf = (const float4*)(pc1 + (size_t)(b * M + p) * 3);
            float4 A = pf[0], Bv = pf[1], C = pf[2];
            dst[0] = make_float4(-2.f * A.x, -2.f * A.y, -2.f * A.z,
                                 (A.x * A.x + A.y * A.y) + A.z * A.z);
            dst[1] = make_float4(-2.f * A.w, -2.f * Bv.x, -2.f * Bv.y,
                                 (A.w * A.w + Bv.x * Bv.x) + Bv.y * Bv.y);
            dst[2] = make_float4(-2.f * Bv.z, -2.f * Bv.w, -2.f * C.x,
                                 (Bv.z * Bv.z + Bv.w * Bv.w) + C.x * C.x);
            dst[3] = make_float4(-2.f * C.y, -2.f * C.z, -2.f * C.w,
                                 (C.y * C.y + C.z * C.z) + C.w * C.w);
        } else {
            #pragma unroll
            for (int u = 0; u < 4; ++u) {
                int pp = p + u;
                float4 v;
                if (pp < M) {
                    const float* s = pc1 + (size_t)(b * M + pp) * 3;
                    float x = s[0], y = s[1], z = s[2];
                    v = make_float4(-2.f * x, -2.f * y, -2.f * z,
                                    (x * x + y * y) + z * z);
                } else {
                    v = make_float4(0.f, 0.f, 0.f, FLT_MAX);
                }
                dst[u] = v;
            }
        }
    }
    __syncthreads();

    // ---- scan: wave w handles 16 queries; lane = (part, chunk) ----
    const int w    = tid >> 6;
    const int lane = tid & 63;
    const int cl   = lane & 15;       // local chunk
    const int part = lane >> 4;       // quarter of the chunk (32 pts)

    float4 qv[QT];
    #pragma unroll
    for (int t = 0; t < QT; ++t) qv[t] = qd[w * QT + t];

    float mm[QT];
    #pragma unroll
    for (int t = 0; t < QT; ++t) mm[t] = FLT_MAX;

    const float4* tp = &tile[cl * CSP + part * 32];
    #pragma unroll 4
    for (int i = 0; i < 32; ++i) {
        const float4 v = tp[i];
        #pragma unroll
        for (int t = 0; t < QT; ++t)
            mm[t] = fminf(mm[t],
                fmaf(qv[t].x, v.x, fmaf(qv[t].y, v.y, fmaf(qv[t].z, v.z, v.w))));
    }

    // merge the 4 parts of each chunk (lane bits 4..5)
    #pragma unroll
    for (int msk = 16; msk <= 32; msk <<= 1) {
        #pragma unroll
        for (int t = 0; t < QT; ++t)
            mm[t] = fminf(mm[t], __shfl_xor(mm[t], msk));
    }

    if (part == 0) {
        const int cg = ctb * CT + cl;         // global chunk id
        #pragma unroll
        for (int t = 0; t < QT; ++t) {
            int qg0 = qb + w * QT + t;
            int qg  = (qg0 < N) ? qg0 : (N - 1);
            cmin[((size_t)b * N + qg) * cstride + cg] = mm[t];
        }
    }
}

// ---------------- K2: threshold + exact rescan + outputs ----------------
// 4 queries per wave, 16 lanes each (all reductions 4 levels, masks 1..8)
__launch_bounds__(256, 8)
__global__ void knn_select(const float* __restrict__ pc0,
                           const float* __restrict__ pc1,
                           const float* __restrict__ flow1,
                           const float* __restrict__ pose0,
                           const float* __restrict__ pose1,
                           const float* __restrict__ cmin,
                           float* __restrict__ out,
                           int B, int N, int M, int cstride)
{
    const int tid  = threadIdx.x;
    const int w    = tid >> 6;
    const int lane = tid & 63;
    const int g    = lane >> 4;        // query group in wave
    const int l    = lane & 15;        // lane within group
    const int b    = blockIdx.y;
    const int q0   = blockIdx.x * 16 + w * 4 + g;
    const bool qvalid = (q0 < N);
    const int q    = qvalid ? q0 : (N - 1);

    // ---- load this group's cmin row slice (wave reads 1KB contiguous) ----
    const int ncc = cstride;
    const size_t row = (size_t)(b * N + q) * cstride;
    float c0, c1, c2, c3;
    if (l * 4 + 3 < ncc) {
        float4 cv = *(const float4*)&cmin[row + l * 4];
        c0 = cv.x; c1 = cv.y; c2 = cv.z; c3 = cv.w;
    } else {
        c0 = (l * 4 + 0 < ncc) ? cmin[row + l * 4 + 0] : FLT_MAX;
        c1 = (l * 4 + 1 < ncc) ? cmin[row + l * 4 + 1] : FLT_MAX;
        c2 = (l * 4 + 2 < ncc) ? cmin[row + l * 4 + 2] : FLT_MAX;
        c3 = (l * 4 + 3 < ncc) ? cmin[row + l * 4 + 3] : FLT_MAX;
    }

    // ---- query transform (redundant per lane) ----
    float R[3][3], tv[3];
    pose_rel(pose0 + b * 16, pose1 + b * 16, R, tv);
    const float px = pc0[(size_t)(b * N + q) * 3 + 0];
    const float py = pc0[(size_t)(b * N + q) * 3 + 1];
    const float pz = pc0[(size_t)(b * N + q) * 3 + 2];
    const float qx = fmaf(R[0][2], pz, fmaf(R[0][1], py, R[0][0] * px)) + tv[0];
    const float qy = fmaf(R[1][2], pz, fmaf(R[1][1], py, R[1][0] * px)) + tv[1];
    const float qz = fmaf(R[2][2], pz, fmaf(R[2][1], py, R[2][0] * px)) + tv[2];
    const float q2 = (qx * qx + qy * qy) + qz * qz;

    // ---- threshold: 3rd-smallest chunk-min within group (4 levels) ----
    float a0 = FLT_MAX, a1 = FLT_MAX, a2 = FLT_MAX;
    sins(c0, a0, a1, a2);
    sins(c1, a0, a1, a2);
    sins(c2, a0, a1, a2);
    sins(c3, a0, a1, a2);
    #pragma unroll
    for (int msk = 1; msk <= 8; msk <<= 1) {
        float o0 = __shfl_xor(a0, msk);
        float o1 = __shfl_xor(a1, msk);
        float o2 = __shfl_xor(a2, msk);
        sins(o0, a0, a1, a2);
        sins(o1, a0, a1, a2);
        sins(o2, a0, a1, a2);
    }
    const float thr = a2 + MARGIN;

    // ---- group chunk mask: 4 bits/lane, OR-butterfly (4 levels) ----
    ull mask = ((ull)(c0 <= thr) << (4 * l + 0))
             | ((ull)(c1 <= thr) << (4 * l + 1))
             | ((ull)(c2 <= thr) << (4 * l + 2))
             | ((ull)(c3 <= thr) << (4 * l + 3));
    #pragma unroll
    for (int msk = 1; msk <= 8; msk <<= 1)
        mask |= __shfl_xor(mask, msk);

    // ---- dense rescan of selected chunks (16 lanes, 8 rounds/chunk) ----
    // even/odd accumulator pair halves the serial ins3k chain
    ull kA0 = KMAX, kA1 = KMAX, kA2 = KMAX;
    ull kB0 = KMAX, kB1 = KMAX, kB2 = KMAX;
    while (mask) {
        const int ck = (int)__builtin_ctzll(mask);
        mask &= mask - 1;
        #pragma unroll
        for (int r = 0; r < CS / 16; ++r) {
            const int m = ck * CS + r * 16 + l;
            if (m < M) {
                const float* pp = pc1 + (size_t)(b * M + m) * 3;
                float x = pp[0], y = pp[1], z = pp[2];
                float r2 = (x * x + y * y) + z * z;
                float cr = fmaf(qz, z, fmaf(qy, y, qx * x));
                float dd = fmaf(-2.0f, cr, q2 + r2);     // exact ref rounding
                ull kk = ((ull)ford(dd) << 32) | (unsigned int)m;
                if (r & 1) ins3k(kk, kB0, kB1, kB2);
                else       ins3k(kk, kA0, kA1, kA2);
            }
        }
    }
    ins3k(kB0, kA0, kA1, kA2);
    ins3k(kB1, kA0, kA1, kA2);
    ins3k(kB2, kA0, kA1, kA2);

    // ---- merge 16 lanes: 4-level butterfly of sorted triples ----
    #pragma unroll
    for (int msk = 1; msk <= 8; msk <<= 1) {
        ull o0 = __shfl_xor(kA0, msk);
        ull o1 = __shfl_xor(kA1, msk);
        ull o2 = __shfl_xor(kA2, msk);
        ins3k(o0, kA0, kA1, kA2);
        ins3k(o1, kA0, kA1, kA2);
        ins3k(o2, kA0, kA1, kA2);
    }

    if (l == 0 && qvalid) {
        // pose_flow
        size_t pf = (size_t)B * N * 3 + (size_t)(b * N + q) * 3;
        out[pf + 0] = qx - px;
        out[pf + 1] = qy - py;
        out[pf + 2] = qz - pz;

        float D0 = funord((unsigned int)(kA0 >> 32));
        float D1 = funord((unsigned int)(kA1 >> 32));
        float D2 = funord((unsigned int)(kA2 >> 32));
        int   i0 = (int)(unsigned int)kA0;
        int   i1 = (int)(unsigned int)kA1;
        int   i2 = (int)(unsigned int)kA2;

        float dd0 = sqrtf(fmaxf(D0, 0.f));
        float dd1 = sqrtf(fmaxf(D1, 0.f));
        float dd2 = sqrtf(fmaxf(D2, 0.f));
        float w0 = 1.0f / (dd0 + 1e-8f);
        float w1 = 1.0f / (dd1 + 1e-8f);
        float w2 = 1.0f / (dd2 + 1e-8f);
        float wsum = (w0 + w1) + w2;
        w0 /= wsum; w1 /= wsum; w2 /= wsum;

        const float* f0 = flow1 + (size_t)(b * M + i0) * 3;
        const float* f1 = flow1 + (size_t)(b * M + i1) * 3;
        const float* f2 = flow1 + (size_t)(b * M + i2) * 3;

        const size_t ob = (size_t)(b * N + q) * 3;
        #pragma unroll
        for (int c = 0; c < 3; ++c) {
            float p0 = w0 * f0[c];
            float p1 = w1 * f1[c];
            float p2 = w2 * f2[c];
            out[ob + c] = (p0 + p1) + p2;
        }
    }
}

extern "C" void kernel_launch(void* const* d_in, const int* in_sizes, int n_in,
                              void* d_out, int out_size, void* d_ws, size_t ws_size,
                              hipStream_t stream) {
    const float* pc0   = (const float*)d_in[0];
    const float* pc1   = (const float*)d_in[1];
    const float* flow1 = (const float*)d_in[2];
    const float* pose0 = (const float*)d_in[3];
    const float* pose1 = (const float*)d_in[4];
    float* out = (float*)d_out;

    const int B = in_sizes[3] / 16;
    const int N = in_sizes[0] / (3 * B);
    const int M = in_sizes[1] / (3 * B);

    const int nct     = (M + TILE_PTS - 1) / TILE_PTS;   // chunk-tiles
    const int cstride = nct * CT;                        // chunk-min row stride

    float* cmin = (float*)d_ws;   // B*N*cstride floats (4 MB at 2x8192x64)

    dim3 g1((N + QB1 - 1) / QB1, nct, B);
    knn_phaseA<<<g1, dim3(256), 0, stream>>>(pc0, pc1, pose0, pose1,
                                             cmin, B, N, M, cstride);

    dim3 g2((N + 15) / 16, B);
    knn_select<<<g2, dim3(256), 0, stream>>>(pc0, pc1, flow1, pose0, pose1,
                                             cmin, out, B, N, M, cstride);
}